// Round 13
// baseline (284.537 us; speedup 1.0000x reference)
//
#include <hip/hip_runtime.h>
#include <hip/hip_bf16.h>
#include <cmath>

#define V 8192
#define NREF 262144
#define NALT 131072
#define NREADS (NREF + NALT)
#define FR 11
#define FI 9
#define HH 256
#define MAX_ALT 10

#define TILE_R 128   // phi rows per block
#define TILE_V 32    // rho variants per block

#define HPITCH 264   // sH pitch (shorts): 528 B rows, 16B-aligned
#define RBPITCH 40   // sRB pitch (shorts)
#define PTP 136      // P^T pitch (shorts): 272 B rows, 16B-aligned
#define CPITCH 776   // sC pitch (shorts)
#define APITCH 264   // sA1/sAgg pitch

// union: sH (67584) + sRB (10240) = 77824 B; sPT (256*PTP*2 = 69632 B)
// overlays both after B3. Static LDS 78336 B -> 2 blocks/CU (measured r8/r12).
#define USMEM_BYTES (TILE_R * HPITCH * 2 + TILE_R * RBPITCH * 2)

typedef short bf16x8 __attribute__((ext_vector_type(8)));
typedef float f32x4  __attribute__((ext_vector_type(4)));

__device__ __forceinline__ float lrelu_(float x) {
    return x > 0.0f ? x : 0.01f * x;
}
__device__ __forceinline__ float sigmoidf_(float x) {
    return __builtin_amdgcn_rcpf(1.0f + __expf(-x));
}
__device__ __forceinline__ unsigned short f2bf_(float f) {
    unsigned int u = __float_as_uint(f);
    u += 0x7FFFu + ((u >> 16) & 1u);
    return (unsigned short)(u >> 16);
}
__device__ __forceinline__ float bf2f_(unsigned short b) {
    return __uint_as_float(((unsigned int)b) << 16);
}
__device__ __forceinline__ unsigned int pk2bf_(float a, float b) {
    union { __hip_bfloat162 h2; unsigned int u; } cvt;
    cvt.h2 = __float22bfloat162_rn(make_float2(a, b));
    return cvt.u;
}

// ---------------------------------------------------------------------------
// Fused prep: 4 transposes (f32->bf16) + phi-W0 pack + accumulator zeroing.
// ---------------------------------------------------------------------------
__global__ __launch_bounds__(256) void prep_kernel(
    const float* __restrict__ phi_W1, const float* __restrict__ rho_W0,
    const float* __restrict__ rho_W1, const float* __restrict__ out_W1,
    const float* __restrict__ phi_W0,
    unsigned short* __restrict__ w1t_phi, unsigned short* __restrict__ w0t,
    unsigned short* __restrict__ w1rt, unsigned short* __restrict__ whT,
    unsigned short* __restrict__ w0pT, float* __restrict__ zbase)
{
    __shared__ unsigned short sT[32][33];
    const int b = blockIdx.x;
    const int t = threadIdx.x;
    if (b < 512) {
        const float* src; unsigned short* dst; int R, C, bx, by;
        if (b < 64)       { src = phi_W1; dst = w1t_phi; R = 256; C = 256; bx = b & 7; by = b >> 3; }
        else if (b < 256) { int i = b - 64;  src = rho_W0; dst = w0t;  R = 768; C = 256; bx = i & 7; by = i >> 3; }
        else if (b < 320) { int i = b - 256; src = rho_W1; dst = w1rt; R = 256; C = 256; bx = i & 7; by = i >> 3; }
        else              { int i = b - 320; int z = i >> 6; i &= 63;
                            src = out_W1 + (size_t)z * HH * HH; dst = whT + (size_t)z * HH * HH;
                            R = 256; C = 256; bx = i & 7; by = i >> 3; }
        const int tx = t & 31, ty = t >> 5;
        const int r0 = by * 32, c0 = bx * 32;
#pragma unroll
        for (int k = 0; k < 4; k++)
            sT[ty + k * 8][tx] = f2bf_(src[(size_t)(r0 + ty + k * 8) * C + c0 + tx]);
        __syncthreads();
#pragma unroll
        for (int k = 0; k < 4; k++)
            dst[(size_t)(c0 + ty + k * 8) * R + r0 + tx] = sT[tx][ty + k * 8];
    } else if (b < 544) {
        const int idx = (b - 512) * 256 + t;
        const int c = idx >> 5, k = idx & 31;
        unsigned short v = 0;
        if (k < FR) v = f2bf_(phi_W0[k * HH + c]);
        else if (k >= 16 && k < 16 + FR) v = f2bf_(phi_W0[(k - 16) * HH + c]);
        w0pT[idx] = v;
    } else {
        const int n4 = (2 * V * HH + 2 * V) / 4;
        float4 z = {0.f, 0.f, 0.f, 0.f};
        for (int i = (b - 544) * 256 + t; i < n4; i += 1024 * 256)
            ((float4*)zbase)[i] = z;
    }
}

// ---------------------------------------------------------------------------
// Kernel A: fused phi MLP + segment sum/count. 512 threads = 8 waves,
// block = 128 reads, 2 blocks/CU. Epilogue: bf16 P^T transpose through LDS
// (overlaying sH+sRB) + serial per-column run walk (wave-uniform branch,
// 1 add/row) -- the leanest of the four measured epilogue families.
// ---------------------------------------------------------------------------
__global__ __launch_bounds__(512, 2) void phi_seg_kernel(
    const float* __restrict__ reads,
    const int* __restrict__ ref_ids, const int* __restrict__ alt_ids,
    const unsigned short* __restrict__ w0pT, const float* __restrict__ b0,
    const unsigned short* __restrict__ w1t, const float* __restrict__ b1,
    float* __restrict__ ref_sums, float* __restrict__ alt_sums,
    int* __restrict__ ref_cnt, int* __restrict__ alt_cnt)
{
    __shared__ __align__(16) unsigned char uSmem[USMEM_BYTES];   // 77824 B
    __shared__ __align__(16) int sSegL[TILE_R];                  // 512 B

    unsigned short* sH  = (unsigned short*)uSmem;
    unsigned short* sRB = (unsigned short*)(uSmem + TILE_R * HPITCH * 2);
    unsigned short* sPT = (unsigned short*)uSmem;   // overlays post-B3

    const int t  = threadIdx.x;
    const int r0 = blockIdx.x * TILE_R;
    const bool is_ref = (r0 < NREF);
    const int* seg_ids = is_ref ? ref_ids : alt_ids;
    const int sbase    = is_ref ? r0 : (r0 - NREF);
    float* sums = is_ref ? ref_sums : alt_sums;
    int*   cnts = is_ref ? ref_cnt  : alt_cnt;

    // ---- stage reads, hi/lo bf16 split: cols 0..10 hi, 16..26 lo ----
    {
        const int row = t & 127, q = t >> 7;   // q = 0..3
        const float* rp = reads + (size_t)(r0 + row) * FR;
        const int nj = (q & 1) ? 3 : 8;
        const int cb = (q & 1) ? 8 : 0;
        unsigned short o[8];
#pragma unroll
        for (int j = 0; j < 8; j++) o[j] = 0;
        if (q < 2) {
            for (int j = 0; j < nj; j++) o[j] = f2bf_(rp[cb + j]);
        } else {
            for (int j = 0; j < nj; j++) {
                float f = rp[cb + j];
                o[j] = f2bf_(f - bf2f_(f2bf_(f)));
            }
        }
        uint4 pk;
        pk.x = (unsigned int)o[0] | ((unsigned int)o[1] << 16);
        pk.y = (unsigned int)o[2] | ((unsigned int)o[3] << 16);
        pk.z = (unsigned int)o[4] | ((unsigned int)o[5] << 16);
        pk.w = (unsigned int)o[6] | ((unsigned int)o[7] << 16);
        *(uint4*)&sRB[row * RBPITCH + q * 8] = pk;
    }
    if (t < TILE_R) sSegL[t] = seg_ids[sbase + t];
    __syncthreads();   // B1

    const int wv   = t >> 6;      // 0..7
    const int lane = t & 63;
    const int lrow = lane & 15;
    const int quad = lane >> 4;

    // per-row count atomics (measured fine in r10)
    if (t < TILE_R) atomicAdd(&cnts[sSegL[t]], 1);

    // ---- GEMM1 via MFMA: wave owns H-cols [wv*32, wv*32+32); N = 128 reads ----
    {
        bf16x8 br[8];
#pragma unroll
        for (int rt = 0; rt < 8; rt++)
            br[rt] = *(const bf16x8*)&sRB[(rt * 16 + lrow) * RBPITCH + quad * 8];

#pragma unroll
        for (int cm = 0; cm < 2; cm++) {
            const bf16x8 aw = *(const bf16x8*)(w0pT + ((wv * 32 + cm * 16 + lrow) << 5) + quad * 8);
            f32x4 c1[8];
#pragma unroll
            for (int rt = 0; rt < 8; rt++)
                c1[rt] = __builtin_amdgcn_mfma_f32_16x16x32_bf16(
                    aw, br[rt], (f32x4){0.f, 0.f, 0.f, 0.f}, 0, 0, 0);

            const float4 bias = *(const float4*)(b0 + wv * 32 + cm * 16 + quad * 4);
#pragma unroll
            for (int rt = 0; rt < 8; rt++) {
                const int r = rt * 16 + lrow;
                uint2 pk;
                pk.x = pk2bf_(lrelu_(c1[rt][0] + bias.x), lrelu_(c1[rt][1] + bias.y));
                pk.y = pk2bf_(lrelu_(c1[rt][2] + bias.z), lrelu_(c1[rt][3] + bias.w));
                *(uint2*)&sH[r * HPITCH + wv * 32 + cm * 16 + quad * 4] = pk;
            }
        }
    }
    __syncthreads();   // B2

    // ---- GEMM2 via MFMA: 128 reads x 32 cols per wave ----
    f32x4 acc[8][2];
#pragma unroll
    for (int mt = 0; mt < 8; mt++)
#pragma unroll
        for (int nt = 0; nt < 2; nt++)
            acc[mt][nt] = (f32x4){0.f, 0.f, 0.f, 0.f};

#pragma unroll
    for (int kk = 0; kk < 8; kk++) {
        const bf16x8 bn0 = *(const bf16x8*)(w1t + (size_t)(wv * 32 + lrow) * HH + kk * 32 + quad * 8);
        const bf16x8 bn1 = *(const bf16x8*)(w1t + (size_t)(wv * 32 + 16 + lrow) * HH + kk * 32 + quad * 8);
#pragma unroll
        for (int mt = 0; mt < 8; mt++) {
            const bf16x8 am = *(const bf16x8*)&sH[(mt * 16 + lrow) * HPITCH + kk * 32 + quad * 8];
            acc[mt][0] = __builtin_amdgcn_mfma_f32_16x16x32_bf16(am, bn0, acc[mt][0], 0, 0, 0);
            acc[mt][1] = __builtin_amdgcn_mfma_f32_16x16x32_bf16(am, bn1, acc[mt][1], 0, 0, 0);
        }
    }

    // ---- sigmoid in regs ----
    const float L2E = 1.44269504f;
#pragma unroll
    for (int nt = 0; nt < 2; nt++) {
        const float nb = -b1[wv * 32 + nt * 16 + lrow] * L2E;
#pragma unroll
        for (int mt = 0; mt < 8; mt++)
#pragma unroll
            for (int r = 0; r < 4; r++) {
                const float e = __builtin_amdgcn_exp2f(fmaf(acc[mt][nt][r], -L2E, nb));
                acc[mt][nt][r] = __builtin_amdgcn_rcpf(1.0f + e);
            }
    }

    __syncthreads();   // B3: sH+sRB dead -> region becomes sPT

    // ---- transpose P to sPT[col][row], bf16 (r2-7 precision: absmax ok) ----
    const int col0 = wv * 32 + lrow;
    const int col1 = wv * 32 + 16 + lrow;
#pragma unroll
    for (int mt = 0; mt < 8; mt++) {
        uint2 p0, p1;
        p0.x = pk2bf_(acc[mt][0][0], acc[mt][0][1]);
        p0.y = pk2bf_(acc[mt][0][2], acc[mt][0][3]);
        p1.x = pk2bf_(acc[mt][1][0], acc[mt][1][1]);
        p1.y = pk2bf_(acc[mt][1][2], acc[mt][1][3]);
        *(uint2*)&sPT[col0 * PTP + mt * 16 + quad * 4] = p0;
        *(uint2*)&sPT[col1 * PTP + mt * 16 + quad * 4] = p1;
    }
    __syncthreads();   // B4: columns complete (cross-wave readers)

    // ---- serial per-column run walk: thread t owns col t&255, 64 rows ----
    {
        const int colw = t & 255;
        const int rb   = (t >> 8) * 64;   // wave-uniform (t>>8 = wv>>2)
        bf16x8 pcol[8];
#pragma unroll
        for (int j = 0; j < 8; j++)
            pcol[j] = *(const bf16x8*)&sPT[colw * PTP + rb + j * 8];

        int cur = sSegL[rb];
        float run = 0.f;
#pragma unroll
        for (int r = 0; r < 64; r++) {
            const int s = sSegL[rb + r];   // LDS broadcast, wave-uniform
            if (s != cur) {
                atomicAdd(&sums[(size_t)cur * HH + colw], run);
                run = 0.f; cur = s;
            }
            run += bf2f_((unsigned short)pcol[r >> 3][r & 7]);
        }
        atomicAdd(&sums[(size_t)cur * HH + colw], run);
    }
}

// ---------------------------------------------------------------------------
// Kernel B: fused MFMA chain (round-6/8 best config).
// ---------------------------------------------------------------------------
__global__ __launch_bounds__(1024, 1) void rho_mfma_kernel(
    const float* __restrict__ info, const int* __restrict__ vtypes,
    const float* __restrict__ om_W0, const float* __restrict__ om_b0,
    const unsigned short* __restrict__ w0t, const float* __restrict__ rho_b0,
    const unsigned short* __restrict__ w1rt, const float* __restrict__ rho_b1,
    const unsigned short* __restrict__ whT, const float* __restrict__ out_b1,
    const float* __restrict__ out_W2, const float* __restrict__ out_b2,
    const float* __restrict__ conf, const float* __restrict__ max_logit,
    const float* __restrict__ ref_sums, const float* __restrict__ alt_sums,
    const int* __restrict__ ref_cnt, const int* __restrict__ alt_cnt,
    float* __restrict__ out)
{
    __shared__ __align__(16) unsigned short sC[TILE_V * CPITCH];
    __shared__ __align__(16) float sInfo[TILE_V][12];
    __shared__ float sRinvR[TILE_V], sRinvA[TILE_V];
    __shared__ float sPart[16][3][TILE_V];

    unsigned short* sA1  = sC;
    unsigned short* sAgg = sC + TILE_V * APITCH;

    const int t  = threadIdx.x;
    const int v0 = blockIdx.x * TILE_V;

    if (t < TILE_V) {
        sRinvR[t] = __builtin_amdgcn_rcpf(fmaxf((float)ref_cnt[v0 + t], 1.0f));
        sRinvA[t] = __builtin_amdgcn_rcpf(fmaxf((float)alt_cnt[v0 + t], 1.0f));
    }
    for (int idx = t; idx < TILE_V * FI; idx += 1024) {
        int i = idx / FI, k = idx - i * FI;
        sInfo[i][k] = info[(size_t)(v0 + i) * FI + k];
    }
    __syncthreads();

    {
        const int c = t & 255, grp = t >> 8;
        float om0r[FI];
#pragma unroll
        for (int k = 0; k < FI; k++) om0r[k] = om_W0[k * HH + c];
        const float omb = om_b0[c];
#pragma unroll
        for (int ii = 0; ii < 8; ii++) {
            const int i = grp * 8 + ii, v = v0 + i;
            float rm = ref_sums[(size_t)v * HH + c] * sRinvR[i];
            float am = alt_sums[(size_t)v * HH + c] * sRinvA[i];
            float a = omb;
#pragma unroll
            for (int k = 0; k < FI; k++) a = fmaf(sInfo[i][k], om0r[k], a);
            sC[i * CPITCH + c]          = f2bf_(rm);
            sC[i * CPITCH + HH + c]     = f2bf_(am);
            sC[i * CPITCH + 2 * HH + c] = f2bf_(sigmoidf_(a));
        }
    }
    __syncthreads();

    const int wv   = t >> 6;
    const int lane = t & 63;
    const int lrow = lane & 15;
    const int quad = lane >> 4;
    const int ncol = wv * 16 + lrow;

    f32x4 p1[2] = {(f32x4){0.f,0.f,0.f,0.f}, (f32x4){0.f,0.f,0.f,0.f}};
#pragma unroll 4
    for (int kk = 0; kk < 24; kk++) {
        bf16x8 a0 = *(const bf16x8*)&sC[lrow * CPITCH + kk * 32 + quad * 8];
        bf16x8 a1 = *(const bf16x8*)&sC[(16 + lrow) * CPITCH + kk * 32 + quad * 8];
        bf16x8 bn = *(const bf16x8*)(w0t + (size_t)ncol * 768 + kk * 32 + quad * 8);
        p1[0] = __builtin_amdgcn_mfma_f32_16x16x32_bf16(a0, bn, p1[0], 0, 0, 0);
        p1[1] = __builtin_amdgcn_mfma_f32_16x16x32_bf16(a1, bn, p1[1], 0, 0, 0);
    }
    __syncthreads();
    {
        const float bb = rho_b0[ncol];
#pragma unroll
        for (int mt = 0; mt < 2; mt++)
#pragma unroll
            for (int r = 0; r < 4; r++) {
                const int row = mt * 16 + quad * 4 + r;
                sA1[row * APITCH + ncol] = f2bf_(lrelu_(p1[mt][r] + bb));
            }
    }
    __syncthreads();

    f32x4 p2[2] = {(f32x4){0.f,0.f,0.f,0.f}, (f32x4){0.f,0.f,0.f,0.f}};
#pragma unroll
    for (int kk = 0; kk < 8; kk++) {
        bf16x8 a0 = *(const bf16x8*)&sA1[lrow * APITCH + kk * 32 + quad * 8];
        bf16x8 a1 = *(const bf16x8*)&sA1[(16 + lrow) * APITCH + kk * 32 + quad * 8];
        bf16x8 bn = *(const bf16x8*)(w1rt + (size_t)ncol * HH + kk * 32 + quad * 8);
        p2[0] = __builtin_amdgcn_mfma_f32_16x16x32_bf16(a0, bn, p2[0], 0, 0, 0);
        p2[1] = __builtin_amdgcn_mfma_f32_16x16x32_bf16(a1, bn, p2[1], 0, 0, 0);
    }
    {
        const float bb = rho_b1[ncol];
#pragma unroll
        for (int mt = 0; mt < 2; mt++)
#pragma unroll
            for (int r = 0; r < 4; r++) {
                const int row = mt * 16 + quad * 4 + r;
                sAgg[row * APITCH + ncol] = f2bf_(p2[mt][r] + bb);
            }
    }
    __syncthreads();

    bf16x8 aF[8][2];
#pragma unroll
    for (int kk = 0; kk < 8; kk++)
#pragma unroll
        for (int mt = 0; mt < 2; mt++)
            aF[kk][mt] = *(const bf16x8*)&sAgg[(mt * 16 + lrow) * APITCH + kk * 32 + quad * 8];

    for (int h = 0; h < 3; h++) {
        f32x4 p3[2] = {(f32x4){0.f,0.f,0.f,0.f}, (f32x4){0.f,0.f,0.f,0.f}};
#pragma unroll
        for (int kk = 0; kk < 8; kk++) {
            bf16x8 bn = *(const bf16x8*)(whT + ((size_t)h * HH + ncol) * HH + kk * 32 + quad * 8);
            p3[0] = __builtin_amdgcn_mfma_f32_16x16x32_bf16(aF[kk][0], bn, p3[0], 0, 0, 0);
            p3[1] = __builtin_amdgcn_mfma_f32_16x16x32_bf16(aF[kk][1], bn, p3[1], 0, 0, 0);
        }
        const float bb = out_b1[h * HH + ncol];
        const float w2 = out_W2[h * HH + ncol];
#pragma unroll
        for (int mt = 0; mt < 2; mt++)
#pragma unroll
            for (int r = 0; r < 4; r++) {
                float v = lrelu_(p3[mt][r] + bb) * w2;
                v += __shfl_down(v, 8);
                v += __shfl_down(v, 4);
                v += __shfl_down(v, 2);
                v += __shfl_down(v, 1);
                if (lrow == 0) sPart[wv][h][mt * 16 + quad * 4 + r] = v;
            }
    }
    __syncthreads();

    if (t < TILE_V) {
        const int v = v0 + t;
        const int ty = vtypes[v];
        float logit = 0.f;
#pragma unroll
        for (int w = 0; w < 16; w++) logit += sPart[w][ty][t];
        logit += out_b2[ty];
        const int tr = min(alt_cnt[v], MAX_ALT);
        logit *= conf[tr];
        const float ml = max_logit[0];
        out[v] = ml * tanhf(logit / ml);
    }
}

// ---------------------------------------------------------------------------
extern "C" void kernel_launch(void* const* d_in, const int* in_sizes, int n_in,
                              void* d_out, int out_size, void* d_ws, size_t ws_size,
                              hipStream_t stream) {
    const float* reads    = (const float*)d_in[0];
    const float* info     = (const float*)d_in[1];
    const int*   ref_ids  = (const int*)d_in[2];
    const int*   alt_ids  = (const int*)d_in[3];
    const int*   vtypes   = (const int*)d_in[4];
    const float* phi_W0   = (const float*)d_in[5];
    const float* phi_b0   = (const float*)d_in[6];
    const float* phi_W1   = (const float*)d_in[7];
    const float* phi_b1   = (const float*)d_in[8];
    const float* om_W0    = (const float*)d_in[9];
    const float* om_b0    = (const float*)d_in[10];
    const float* rho_W0   = (const float*)d_in[11];
    const float* rho_b0   = (const float*)d_in[12];
    const float* rho_W1   = (const float*)d_in[13];
    const float* rho_b1   = (const float*)d_in[14];
    const float* out_W1   = (const float*)d_in[15];
    const float* out_b1   = (const float*)d_in[16];
    const float* out_W2   = (const float*)d_in[17];
    const float* out_b2   = (const float*)d_in[18];
    const float* conf     = (const float*)d_in[19];
    const float* max_lg   = (const float*)d_in[20];
    float* out = (float*)d_out;

    float* ref_sums = (float*)d_ws;
    float* alt_sums = ref_sums + (size_t)V * HH;
    int*   ref_cnt  = (int*)(alt_sums + (size_t)V * HH);
    int*   alt_cnt  = ref_cnt + V;
    unsigned short* w1t_phi = (unsigned short*)(alt_cnt + V);
    unsigned short* w0t     = w1t_phi + (size_t)HH * HH;
    unsigned short* w1rt    = w0t + (size_t)HH * 768;
    unsigned short* whT     = w1rt + (size_t)HH * HH;
    unsigned short* w0pT    = whT + (size_t)3 * HH * HH;

    prep_kernel<<<1568, 256, 0, stream>>>(phi_W1, rho_W0, rho_W1, out_W1, phi_W0,
                                          w1t_phi, w0t, w1rt, whT, w0pT,
                                          (float*)d_ws);

    phi_seg_kernel<<<NREADS / TILE_R, 512, 0, stream>>>(
        reads, ref_ids, alt_ids, w0pT, phi_b0, w1t_phi, phi_b1,
        ref_sums, alt_sums, ref_cnt, alt_cnt);

    rho_mfma_kernel<<<V / TILE_V, 1024, 0, stream>>>(
        info, vtypes, om_W0, om_b0, w0t, rho_b0, w1rt, rho_b1,
        whT, out_b1, out_W2, out_b2, conf, max_lg,
        ref_sums, alt_sums, ref_cnt, alt_cnt, out);
}

// Round 14
// 278.886 us; speedup vs baseline: 1.0203x; 1.0203x over previous
//
#include <hip/hip_runtime.h>
#include <hip/hip_bf16.h>
#include <cmath>

#define V 8192
#define NREF 262144
#define NALT 131072
#define NREADS (NREF + NALT)
#define FR 11
#define FI 9
#define HH 256
#define MAX_ALT 10

#define TILE_R 128   // phi rows per block
#define TILE_V 32    // rho variants per block

#define HPITCH 264   // sH pitch (shorts): 528 B rows, 16B-aligned
#define RBPITCH 40   // sRB pitch (shorts)
#define PTP 136      // P^T pitch (shorts): 272 B rows, 16B-aligned
#define CPITCH 776   // sC pitch (shorts)
#define APITCH 264   // sA1/sAgg pitch

// union: sH (67584) + sRB (10240) = 77824 B; sPT (69632 B) overlays post-B3.
#define USMEM_BYTES (TILE_R * HPITCH * 2 + TILE_R * RBPITCH * 2)

typedef short bf16x8 __attribute__((ext_vector_type(8)));
typedef float f32x4  __attribute__((ext_vector_type(4)));

__device__ __forceinline__ float lrelu_(float x) {
    return x > 0.0f ? x : 0.01f * x;
}
__device__ __forceinline__ float sigmoidf_(float x) {
    return __builtin_amdgcn_rcpf(1.0f + __expf(-x));
}
__device__ __forceinline__ unsigned short f2bf_(float f) {
    unsigned int u = __float_as_uint(f);
    u += 0x7FFFu + ((u >> 16) & 1u);
    return (unsigned short)(u >> 16);
}
__device__ __forceinline__ float bf2f_(unsigned short b) {
    return __uint_as_float(((unsigned int)b) << 16);
}
__device__ __forceinline__ unsigned int pk2bf_(float a, float b) {
    union { __hip_bfloat162 h2; unsigned int u; } cvt;
    cvt.h2 = __float22bfloat162_rn(make_float2(a, b));
    return cvt.u;
}

// ---------------------------------------------------------------------------
// Fused prep: 4 transposes (f32->bf16) + phi-W0 pack + accumulator zeroing.
// ---------------------------------------------------------------------------
__global__ __launch_bounds__(256) void prep_kernel(
    const float* __restrict__ phi_W1, const float* __restrict__ rho_W0,
    const float* __restrict__ rho_W1, const float* __restrict__ out_W1,
    const float* __restrict__ phi_W0,
    unsigned short* __restrict__ w1t_phi, unsigned short* __restrict__ w0t,
    unsigned short* __restrict__ w1rt, unsigned short* __restrict__ whT,
    unsigned short* __restrict__ w0pT, float* __restrict__ zbase)
{
    __shared__ unsigned short sT[32][33];
    const int b = blockIdx.x;
    const int t = threadIdx.x;
    if (b < 512) {
        const float* src; unsigned short* dst; int R, C, bx, by;
        if (b < 64)       { src = phi_W1; dst = w1t_phi; R = 256; C = 256; bx = b & 7; by = b >> 3; }
        else if (b < 256) { int i = b - 64;  src = rho_W0; dst = w0t;  R = 768; C = 256; bx = i & 7; by = i >> 3; }
        else if (b < 320) { int i = b - 256; src = rho_W1; dst = w1rt; R = 256; C = 256; bx = i & 7; by = i >> 3; }
        else              { int i = b - 320; int z = i >> 6; i &= 63;
                            src = out_W1 + (size_t)z * HH * HH; dst = whT + (size_t)z * HH * HH;
                            R = 256; C = 256; bx = i & 7; by = i >> 3; }
        const int tx = t & 31, ty = t >> 5;
        const int r0 = by * 32, c0 = bx * 32;
#pragma unroll
        for (int k = 0; k < 4; k++)
            sT[ty + k * 8][tx] = f2bf_(src[(size_t)(r0 + ty + k * 8) * C + c0 + tx]);
        __syncthreads();
#pragma unroll
        for (int k = 0; k < 4; k++)
            dst[(size_t)(c0 + ty + k * 8) * R + r0 + tx] = sT[tx][ty + k * 8];
    } else if (b < 544) {
        const int idx = (b - 512) * 256 + t;
        const int c = idx >> 5, k = idx & 31;
        unsigned short v = 0;
        if (k < FR) v = f2bf_(phi_W0[k * HH + c]);
        else if (k >= 16 && k < 16 + FR) v = f2bf_(phi_W0[(k - 16) * HH + c]);
        w0pT[idx] = v;
    } else {
        const int n4 = (2 * V * HH + 2 * V) / 4;
        float4 z = {0.f, 0.f, 0.f, 0.f};
        for (int i = (b - 544) * 256 + t; i < n4; i += 1024 * 256)
            ((float4*)zbase)[i] = z;
    }
}

// ---------------------------------------------------------------------------
// Kernel A: fused phi MLP + segment sum/count. 512 threads = 8 waves,
// block = 128 reads, 2 blocks/CU. Epilogue: bf16 P^T transpose + BITMASK
// WALK: run boundaries in an SGPR 64-bit mask (built once via __ballot),
// inner loop = 1 v_add/row, s_bitcmp branch, LDS read only at boundaries.
// ---------------------------------------------------------------------------
__global__ __launch_bounds__(512, 2) void phi_seg_kernel(
    const float* __restrict__ reads,
    const int* __restrict__ ref_ids, const int* __restrict__ alt_ids,
    const unsigned short* __restrict__ w0pT, const float* __restrict__ b0,
    const unsigned short* __restrict__ w1t, const float* __restrict__ b1,
    float* __restrict__ ref_sums, float* __restrict__ alt_sums,
    int* __restrict__ ref_cnt, int* __restrict__ alt_cnt)
{
    __shared__ __align__(16) unsigned char uSmem[USMEM_BYTES];   // 77824 B
    __shared__ __align__(16) int sSegL[TILE_R];                  // 512 B

    unsigned short* sH  = (unsigned short*)uSmem;
    unsigned short* sRB = (unsigned short*)(uSmem + TILE_R * HPITCH * 2);
    unsigned short* sPT = (unsigned short*)uSmem;   // overlays post-B3

    const int t  = threadIdx.x;
    const int r0 = blockIdx.x * TILE_R;
    const bool is_ref = (r0 < NREF);
    const int* seg_ids = is_ref ? ref_ids : alt_ids;
    const int sbase    = is_ref ? r0 : (r0 - NREF);
    float* sums = is_ref ? ref_sums : alt_sums;
    int*   cnts = is_ref ? ref_cnt  : alt_cnt;

    // ---- stage reads, hi/lo bf16 split: cols 0..10 hi, 16..26 lo ----
    {
        const int row = t & 127, q = t >> 7;   // q = 0..3
        const float* rp = reads + (size_t)(r0 + row) * FR;
        const int nj = (q & 1) ? 3 : 8;
        const int cb = (q & 1) ? 8 : 0;
        unsigned short o[8];
#pragma unroll
        for (int j = 0; j < 8; j++) o[j] = 0;
        if (q < 2) {
            for (int j = 0; j < nj; j++) o[j] = f2bf_(rp[cb + j]);
        } else {
            for (int j = 0; j < nj; j++) {
                float f = rp[cb + j];
                o[j] = f2bf_(f - bf2f_(f2bf_(f)));
            }
        }
        uint4 pk;
        pk.x = (unsigned int)o[0] | ((unsigned int)o[1] << 16);
        pk.y = (unsigned int)o[2] | ((unsigned int)o[3] << 16);
        pk.z = (unsigned int)o[4] | ((unsigned int)o[5] << 16);
        pk.w = (unsigned int)o[6] | ((unsigned int)o[7] << 16);
        *(uint4*)&sRB[row * RBPITCH + q * 8] = pk;
    }
    if (t < TILE_R) sSegL[t] = seg_ids[sbase + t];
    __syncthreads();   // B1

    const int wv   = t >> 6;      // 0..7
    const int lane = t & 63;
    const int lrow = lane & 15;
    const int quad = lane >> 4;

    // per-row count atomics (measured fine in r10/r13)
    if (t < TILE_R) atomicAdd(&cnts[sSegL[t]], 1);

    // ---- GEMM1 via MFMA: wave owns H-cols [wv*32, wv*32+32); N = 128 reads ----
    {
        bf16x8 br[8];
#pragma unroll
        for (int rt = 0; rt < 8; rt++)
            br[rt] = *(const bf16x8*)&sRB[(rt * 16 + lrow) * RBPITCH + quad * 8];

#pragma unroll
        for (int cm = 0; cm < 2; cm++) {
            const bf16x8 aw = *(const bf16x8*)(w0pT + ((wv * 32 + cm * 16 + lrow) << 5) + quad * 8);
            f32x4 c1[8];
#pragma unroll
            for (int rt = 0; rt < 8; rt++)
                c1[rt] = __builtin_amdgcn_mfma_f32_16x16x32_bf16(
                    aw, br[rt], (f32x4){0.f, 0.f, 0.f, 0.f}, 0, 0, 0);

            const float4 bias = *(const float4*)(b0 + wv * 32 + cm * 16 + quad * 4);
#pragma unroll
            for (int rt = 0; rt < 8; rt++) {
                const int r = rt * 16 + lrow;
                uint2 pk;
                pk.x = pk2bf_(lrelu_(c1[rt][0] + bias.x), lrelu_(c1[rt][1] + bias.y));
                pk.y = pk2bf_(lrelu_(c1[rt][2] + bias.z), lrelu_(c1[rt][3] + bias.w));
                *(uint2*)&sH[r * HPITCH + wv * 32 + cm * 16 + quad * 4] = pk;
            }
        }
    }
    __syncthreads();   // B2

    // ---- GEMM2 via MFMA: 128 reads x 32 cols per wave ----
    f32x4 acc[8][2];
#pragma unroll
    for (int mt = 0; mt < 8; mt++)
#pragma unroll
        for (int nt = 0; nt < 2; nt++)
            acc[mt][nt] = (f32x4){0.f, 0.f, 0.f, 0.f};

#pragma unroll
    for (int kk = 0; kk < 8; kk++) {
        const bf16x8 bn0 = *(const bf16x8*)(w1t + (size_t)(wv * 32 + lrow) * HH + kk * 32 + quad * 8);
        const bf16x8 bn1 = *(const bf16x8*)(w1t + (size_t)(wv * 32 + 16 + lrow) * HH + kk * 32 + quad * 8);
#pragma unroll
        for (int mt = 0; mt < 8; mt++) {
            const bf16x8 am = *(const bf16x8*)&sH[(mt * 16 + lrow) * HPITCH + kk * 32 + quad * 8];
            acc[mt][0] = __builtin_amdgcn_mfma_f32_16x16x32_bf16(am, bn0, acc[mt][0], 0, 0, 0);
            acc[mt][1] = __builtin_amdgcn_mfma_f32_16x16x32_bf16(am, bn1, acc[mt][1], 0, 0, 0);
        }
    }

    // ---- sigmoid in regs ----
    const float L2E = 1.44269504f;
#pragma unroll
    for (int nt = 0; nt < 2; nt++) {
        const float nb = -b1[wv * 32 + nt * 16 + lrow] * L2E;
#pragma unroll
        for (int mt = 0; mt < 8; mt++)
#pragma unroll
            for (int r = 0; r < 4; r++) {
                const float e = __builtin_amdgcn_exp2f(fmaf(acc[mt][nt][r], -L2E, nb));
                acc[mt][nt][r] = __builtin_amdgcn_rcpf(1.0f + e);
            }
    }

    __syncthreads();   // B3: sH+sRB dead -> region becomes sPT

    // ---- transpose P to sPT[col][row], bf16 (r13 precision: absmax ok) ----
    const int col0 = wv * 32 + lrow;
    const int col1 = wv * 32 + 16 + lrow;
#pragma unroll
    for (int mt = 0; mt < 8; mt++) {
        uint2 p0, p1;
        p0.x = pk2bf_(acc[mt][0][0], acc[mt][0][1]);
        p0.y = pk2bf_(acc[mt][0][2], acc[mt][0][3]);
        p1.x = pk2bf_(acc[mt][1][0], acc[mt][1][1]);
        p1.y = pk2bf_(acc[mt][1][2], acc[mt][1][3]);
        *(uint2*)&sPT[col0 * PTP + mt * 16 + quad * 4] = p0;
        *(uint2*)&sPT[col1 * PTP + mt * 16 + quad * 4] = p1;
    }
    __syncthreads();   // B4: cross-wave column readers

    // ---- bitmask walk: thread t owns col t&255 over 64 rows (grp = t>>8) ----
    {
        const int colw = t & 255;
        const int rb   = (t >> 8) * 64;   // wave-uniform

        // boundary mask (wave-uniform, lands in SGPR pair)
        const int rowseg  = sSegL[rb + lane];
        const int prevseg = (lane == 0) ? (rowseg + 1) : sSegL[rb + lane - 1];
        const unsigned long long m = __ballot(rowseg != prevseg);

        bf16x8 pcol[8];
#pragma unroll
        for (int j = 0; j < 8; j++)
            pcol[j] = *(const bf16x8*)&sPT[colw * PTP + rb + j * 8];

        int cur = sSegL[rb];
        float run = bf2f_((unsigned short)pcol[0][0]);   // row 0
#pragma unroll
        for (int r = 1; r < 64; r++) {
            if (m & (1ull << r)) {          // wave-uniform: s_bitcmp + branch
                atomicAdd(&sums[(size_t)cur * HH + colw], run);
                run = 0.f;
                cur = sSegL[rb + r];
            }
            run += bf2f_((unsigned short)pcol[r >> 3][r & 7]);
        }
        atomicAdd(&sums[(size_t)cur * HH + colw], run);
    }
}

// ---------------------------------------------------------------------------
// Kernel B: fused MFMA chain (round-6/8 best config).
// ---------------------------------------------------------------------------
__global__ __launch_bounds__(1024, 1) void rho_mfma_kernel(
    const float* __restrict__ info, const int* __restrict__ vtypes,
    const float* __restrict__ om_W0, const float* __restrict__ om_b0,
    const unsigned short* __restrict__ w0t, const float* __restrict__ rho_b0,
    const unsigned short* __restrict__ w1rt, const float* __restrict__ rho_b1,
    const unsigned short* __restrict__ whT, const float* __restrict__ out_b1,
    const float* __restrict__ out_W2, const float* __restrict__ out_b2,
    const float* __restrict__ conf, const float* __restrict__ max_logit,
    const float* __restrict__ ref_sums, const float* __restrict__ alt_sums,
    const int* __restrict__ ref_cnt, const int* __restrict__ alt_cnt,
    float* __restrict__ out)
{
    __shared__ __align__(16) unsigned short sC[TILE_V * CPITCH];
    __shared__ __align__(16) float sInfo[TILE_V][12];
    __shared__ float sRinvR[TILE_V], sRinvA[TILE_V];
    __shared__ float sPart[16][3][TILE_V];

    unsigned short* sA1  = sC;
    unsigned short* sAgg = sC + TILE_V * APITCH;

    const int t  = threadIdx.x;
    const int v0 = blockIdx.x * TILE_V;

    if (t < TILE_V) {
        sRinvR[t] = __builtin_amdgcn_rcpf(fmaxf((float)ref_cnt[v0 + t], 1.0f));
        sRinvA[t] = __builtin_amdgcn_rcpf(fmaxf((float)alt_cnt[v0 + t], 1.0f));
    }
    for (int idx = t; idx < TILE_V * FI; idx += 1024) {
        int i = idx / FI, k = idx - i * FI;
        sInfo[i][k] = info[(size_t)(v0 + i) * FI + k];
    }
    __syncthreads();

    {
        const int c = t & 255, grp = t >> 8;
        float om0r[FI];
#pragma unroll
        for (int k = 0; k < FI; k++) om0r[k] = om_W0[k * HH + c];
        const float omb = om_b0[c];
#pragma unroll
        for (int ii = 0; ii < 8; ii++) {
            const int i = grp * 8 + ii, v = v0 + i;
            float rm = ref_sums[(size_t)v * HH + c] * sRinvR[i];
            float am = alt_sums[(size_t)v * HH + c] * sRinvA[i];
            float a = omb;
#pragma unroll
            for (int k = 0; k < FI; k++) a = fmaf(sInfo[i][k], om0r[k], a);
            sC[i * CPITCH + c]          = f2bf_(rm);
            sC[i * CPITCH + HH + c]     = f2bf_(am);
            sC[i * CPITCH + 2 * HH + c] = f2bf_(sigmoidf_(a));
        }
    }
    __syncthreads();

    const int wv   = t >> 6;
    const int lane = t & 63;
    const int lrow = lane & 15;
    const int quad = lane >> 4;
    const int ncol = wv * 16 + lrow;

    f32x4 p1[2] = {(f32x4){0.f,0.f,0.f,0.f}, (f32x4){0.f,0.f,0.f,0.f}};
#pragma unroll 4
    for (int kk = 0; kk < 24; kk++) {
        bf16x8 a0 = *(const bf16x8*)&sC[lrow * CPITCH + kk * 32 + quad * 8];
        bf16x8 a1 = *(const bf16x8*)&sC[(16 + lrow) * CPITCH + kk * 32 + quad * 8];
        bf16x8 bn = *(const bf16x8*)(w0t + (size_t)ncol * 768 + kk * 32 + quad * 8);
        p1[0] = __builtin_amdgcn_mfma_f32_16x16x32_bf16(a0, bn, p1[0], 0, 0, 0);
        p1[1] = __builtin_amdgcn_mfma_f32_16x16x32_bf16(a1, bn, p1[1], 0, 0, 0);
    }
    __syncthreads();
    {
        const float bb = rho_b0[ncol];
#pragma unroll
        for (int mt = 0; mt < 2; mt++)
#pragma unroll
            for (int r = 0; r < 4; r++) {
                const int row = mt * 16 + quad * 4 + r;
                sA1[row * APITCH + ncol] = f2bf_(lrelu_(p1[mt][r] + bb));
            }
    }
    __syncthreads();

    f32x4 p2[2] = {(f32x4){0.f,0.f,0.f,0.f}, (f32x4){0.f,0.f,0.f,0.f}};
#pragma unroll
    for (int kk = 0; kk < 8; kk++) {
        bf16x8 a0 = *(const bf16x8*)&sA1[lrow * APITCH + kk * 32 + quad * 8];
        bf16x8 a1 = *(const bf16x8*)&sA1[(16 + lrow) * APITCH + kk * 32 + quad * 8];
        bf16x8 bn = *(const bf16x8*)(w1rt + (size_t)ncol * HH + kk * 32 + quad * 8);
        p2[0] = __builtin_amdgcn_mfma_f32_16x16x32_bf16(a0, bn, p2[0], 0, 0, 0);
        p2[1] = __builtin_amdgcn_mfma_f32_16x16x32_bf16(a1, bn, p2[1], 0, 0, 0);
    }
    {
        const float bb = rho_b1[ncol];
#pragma unroll
        for (int mt = 0; mt < 2; mt++)
#pragma unroll
            for (int r = 0; r < 4; r++) {
                const int row = mt * 16 + quad * 4 + r;
                sAgg[row * APITCH + ncol] = f2bf_(p2[mt][r] + bb);
            }
    }
    __syncthreads();

    bf16x8 aF[8][2];
#pragma unroll
    for (int kk = 0; kk < 8; kk++)
#pragma unroll
        for (int mt = 0; mt < 2; mt++)
            aF[kk][mt] = *(const bf16x8*)&sAgg[(mt * 16 + lrow) * APITCH + kk * 32 + quad * 8];

    for (int h = 0; h < 3; h++) {
        f32x4 p3[2] = {(f32x4){0.f,0.f,0.f,0.f}, (f32x4){0.f,0.f,0.f,0.f}};
#pragma unroll
        for (int kk = 0; kk < 8; kk++) {
            bf16x8 bn = *(const bf16x8*)(whT + ((size_t)h * HH + ncol) * HH + kk * 32 + quad * 8);
            p3[0] = __builtin_amdgcn_mfma_f32_16x16x32_bf16(aF[kk][0], bn, p3[0], 0, 0, 0);
            p3[1] = __builtin_amdgcn_mfma_f32_16x16x32_bf16(aF[kk][1], bn, p3[1], 0, 0, 0);
        }
        const float bb = out_b1[h * HH + ncol];
        const float w2 = out_W2[h * HH + ncol];
#pragma unroll
        for (int mt = 0; mt < 2; mt++)
#pragma unroll
            for (int r = 0; r < 4; r++) {
                float v = lrelu_(p3[mt][r] + bb) * w2;
                v += __shfl_down(v, 8);
                v += __shfl_down(v, 4);
                v += __shfl_down(v, 2);
                v += __shfl_down(v, 1);
                if (lrow == 0) sPart[wv][h][mt * 16 + quad * 4 + r] = v;
            }
    }
    __syncthreads();

    if (t < TILE_V) {
        const int v = v0 + t;
        const int ty = vtypes[v];
        float logit = 0.f;
#pragma unroll
        for (int w = 0; w < 16; w++) logit += sPart[w][ty][t];
        logit += out_b2[ty];
        const int tr = min(alt_cnt[v], MAX_ALT);
        logit *= conf[tr];
        const float ml = max_logit[0];
        out[v] = ml * tanhf(logit / ml);
    }
}

// ---------------------------------------------------------------------------
extern "C" void kernel_launch(void* const* d_in, const int* in_sizes, int n_in,
                              void* d_out, int out_size, void* d_ws, size_t ws_size,
                              hipStream_t stream) {
    const float* reads    = (const float*)d_in[0];
    const float* info     = (const float*)d_in[1];
    const int*   ref_ids  = (const int*)d_in[2];
    const int*   alt_ids  = (const int*)d_in[3];
    const int*   vtypes   = (const int*)d_in[4];
    const float* phi_W0   = (const float*)d_in[5];
    const float* phi_b0   = (const float*)d_in[6];
    const float* phi_W1   = (const float*)d_in[7];
    const float* phi_b1   = (const float*)d_in[8];
    const float* om_W0    = (const float*)d_in[9];
    const float* om_b0    = (const float*)d_in[10];
    const float* rho_W0   = (const float*)d_in[11];
    const float* rho_b0   = (const float*)d_in[12];
    const float* rho_W1   = (const float*)d_in[13];
    const float* rho_b1   = (const float*)d_in[14];
    const float* out_W1   = (const float*)d_in[15];
    const float* out_b1   = (const float*)d_in[16];
    const float* out_W2   = (const float*)d_in[17];
    const float* out_b2   = (const float*)d_in[18];
    const float* conf     = (const float*)d_in[19];
    const float* max_lg   = (const float*)d_in[20];
    float* out = (float*)d_out;

    float* ref_sums = (float*)d_ws;
    float* alt_sums = ref_sums + (size_t)V * HH;
    int*   ref_cnt  = (int*)(alt_sums + (size_t)V * HH);
    int*   alt_cnt  = ref_cnt + V;
    unsigned short* w1t_phi = (unsigned short*)(alt_cnt + V);
    unsigned short* w0t     = w1t_phi + (size_t)HH * HH;
    unsigned short* w1rt    = w0t + (size_t)HH * 768;
    unsigned short* whT     = w1rt + (size_t)HH * HH;
    unsigned short* w0pT    = whT + (size_t)3 * HH * HH;

    prep_kernel<<<1568, 256, 0, stream>>>(phi_W1, rho_W0, rho_W1, out_W1, phi_W0,
                                          w1t_phi, w0t, w1rt, whT, w0pT,
                                          (float*)d_ws);

    phi_seg_kernel<<<NREADS / TILE_R, 512, 0, stream>>>(
        reads, ref_ids, alt_ids, w0pT, phi_b0, w1t_phi, phi_b1,
        ref_sums, alt_sums, ref_cnt, alt_cnt);

    rho_mfma_kernel<<<V / TILE_V, 1024, 0, stream>>>(
        info, vtypes, om_W0, om_b0, w0t, rho_b0, w1rt, rho_b1,
        whT, out_b1, out_W2, out_b2, conf, max_lg,
        ref_sums, alt_sums, ref_cnt, alt_cnt, out);
}

// Round 15
// 246.582 us; speedup vs baseline: 1.1539x; 1.1310x over previous
//
#include <hip/hip_runtime.h>
#include <hip/hip_bf16.h>
#include <cmath>

#define V 8192
#define NREF 262144
#define NALT 131072
#define NREADS (NREF + NALT)
#define FR 11
#define FI 9
#define HH 256
#define MAX_ALT 10

#define TILE_R 128   // phi rows per block
#define TILE_V 32    // rho variants per block

#define HPITCH 264   // sH pitch (shorts): 528 B rows, 16B-aligned
#define RBPITCH 40   // sRB pitch (shorts)
#define CPITCH 776   // sC pitch (shorts)
#define APITCH 264   // sA1/sAgg pitch

typedef short bf16x8 __attribute__((ext_vector_type(8)));
typedef float f32x4  __attribute__((ext_vector_type(4)));

__device__ __forceinline__ float sigmoidf_(float x) {
    return __builtin_amdgcn_rcpf(1.0f + __expf(-x));
}
__device__ __forceinline__ float lrelu_(float x) {
    return x > 0.0f ? x : 0.01f * x;
}
__device__ __forceinline__ unsigned short f2bf_(float f) {
    unsigned int u = __float_as_uint(f);
    u += 0x7FFFu + ((u >> 16) & 1u);
    return (unsigned short)(u >> 16);
}
__device__ __forceinline__ float bf2f_(unsigned short b) {
    return __uint_as_float(((unsigned int)b) << 16);
}
__device__ __forceinline__ unsigned int pk2bf_(float a, float b) {
    union { __hip_bfloat162 h2; unsigned int u; } cvt;
    cvt.h2 = __float22bfloat162_rn(make_float2(a, b));
    return cvt.u;
}

// ---------------------------------------------------------------------------
// Fused prep: 4 transposes (f32->bf16) + phi-W0 pack + accumulator zeroing
// (r12 structure: no separate memset node).
// ---------------------------------------------------------------------------
__global__ __launch_bounds__(256) void prep_kernel(
    const float* __restrict__ phi_W1, const float* __restrict__ rho_W0,
    const float* __restrict__ rho_W1, const float* __restrict__ out_W1,
    const float* __restrict__ phi_W0,
    unsigned short* __restrict__ w1t_phi, unsigned short* __restrict__ w0t,
    unsigned short* __restrict__ w1rt, unsigned short* __restrict__ whT,
    unsigned short* __restrict__ w0pT, float* __restrict__ zbase)
{
    __shared__ unsigned short sT[32][33];
    const int b = blockIdx.x;
    const int t = threadIdx.x;
    if (b < 512) {
        const float* src; unsigned short* dst; int R, C, bx, by;
        if (b < 64)       { src = phi_W1; dst = w1t_phi; R = 256; C = 256; bx = b & 7; by = b >> 3; }
        else if (b < 256) { int i = b - 64;  src = rho_W0; dst = w0t;  R = 768; C = 256; bx = i & 7; by = i >> 3; }
        else if (b < 320) { int i = b - 256; src = rho_W1; dst = w1rt; R = 256; C = 256; bx = i & 7; by = i >> 3; }
        else              { int i = b - 320; int z = i >> 6; i &= 63;
                            src = out_W1 + (size_t)z * HH * HH; dst = whT + (size_t)z * HH * HH;
                            R = 256; C = 256; bx = i & 7; by = i >> 3; }
        const int tx = t & 31, ty = t >> 5;
        const int r0 = by * 32, c0 = bx * 32;
#pragma unroll
        for (int k = 0; k < 4; k++)
            sT[ty + k * 8][tx] = f2bf_(src[(size_t)(r0 + ty + k * 8) * C + c0 + tx]);
        __syncthreads();
#pragma unroll
        for (int k = 0; k < 4; k++)
            dst[(size_t)(c0 + ty + k * 8) * R + r0 + tx] = sT[tx][ty + k * 8];
    } else if (b < 544) {
        const int idx = (b - 512) * 256 + t;
        const int c = idx >> 5, k = idx & 31;
        unsigned short v = 0;
        if (k < FR) v = f2bf_(phi_W0[k * HH + c]);
        else if (k >= 16 && k < 16 + FR) v = f2bf_(phi_W0[(k - 16) * HH + c]);
        w0pT[idx] = v;
    } else {
        const int n4 = (2 * V * HH + 2 * V) / 4;
        float4 z = {0.f, 0.f, 0.f, 0.f};
        for (int i = (b - 544) * 256 + t; i < n4; i += 1024 * 256)
            ((float4*)zbase)[i] = z;
    }
}

// ---------------------------------------------------------------------------
// Kernel A: fused phi MLP + segment sum/count — EXACT round-8 structure
// (best measured: 131 us). 512 threads = 8 waves, block = 128 reads,
// 2 blocks/CU. Epilogue: ballot-driven run-compressed range-mask reduction,
// acc stays in registers (no LDS transpose).
// ---------------------------------------------------------------------------
__global__ __launch_bounds__(512, 2) void phi_seg_kernel(
    const float* __restrict__ reads,
    const int* __restrict__ ref_ids, const int* __restrict__ alt_ids,
    const unsigned short* __restrict__ w0pT, const float* __restrict__ b0,
    const unsigned short* __restrict__ w1t, const float* __restrict__ b1,
    float* __restrict__ ref_sums, float* __restrict__ alt_sums,
    int* __restrict__ ref_cnt, int* __restrict__ alt_cnt)
{
    __shared__ __align__(16) unsigned short sH[TILE_R * HPITCH];   // 67584 B
    __shared__ __align__(16) unsigned short sRB[TILE_R * RBPITCH]; // 10240 B

    const int t  = threadIdx.x;
    const int r0 = blockIdx.x * TILE_R;
    const bool is_ref = (r0 < NREF);
    const int* seg_ids = is_ref ? ref_ids : alt_ids;
    const int sbase    = is_ref ? r0 : (r0 - NREF);
    float* sums = is_ref ? ref_sums : alt_sums;
    int*   cnts = is_ref ? ref_cnt  : alt_cnt;

    // ---- stage reads, hi/lo bf16 split: cols 0..10 hi, 16..26 lo ----
    {
        const int row = t & 127, q = t >> 7;   // q = 0..3
        const float* rp = reads + (size_t)(r0 + row) * FR;
        const int nj = (q & 1) ? 3 : 8;
        const int cb = (q & 1) ? 8 : 0;
        unsigned short o[8];
#pragma unroll
        for (int j = 0; j < 8; j++) o[j] = 0;
        if (q < 2) {
            for (int j = 0; j < nj; j++) o[j] = f2bf_(rp[cb + j]);
        } else {
            for (int j = 0; j < nj; j++) {
                float f = rp[cb + j];
                o[j] = f2bf_(f - bf2f_(f2bf_(f)));
            }
        }
        uint4 pk;
        pk.x = (unsigned int)o[0] | ((unsigned int)o[1] << 16);
        pk.y = (unsigned int)o[2] | ((unsigned int)o[3] << 16);
        pk.z = (unsigned int)o[4] | ((unsigned int)o[5] << 16);
        pk.w = (unsigned int)o[6] | ((unsigned int)o[7] << 16);
        *(uint4*)&sRB[row * RBPITCH + q * 8] = pk;
    }
    __syncthreads();   // B1

    const int wv   = t >> 6;      // 0..7
    const int lane = t & 63;
    const int lrow = lane & 15;
    const int quad = lane >> 4;

    // ---- GEMM1 via MFMA: wave owns H-cols [wv*32, wv*32+32); N = 128 reads ----
    {
        bf16x8 br[8];
#pragma unroll
        for (int rt = 0; rt < 8; rt++)
            br[rt] = *(const bf16x8*)&sRB[(rt * 16 + lrow) * RBPITCH + quad * 8];

#pragma unroll
        for (int cm = 0; cm < 2; cm++) {
            const bf16x8 aw = *(const bf16x8*)(w0pT + ((wv * 32 + cm * 16 + lrow) << 5) + quad * 8);
            f32x4 c1[8];
#pragma unroll
            for (int rt = 0; rt < 8; rt++)
                c1[rt] = __builtin_amdgcn_mfma_f32_16x16x32_bf16(
                    aw, br[rt], (f32x4){0.f, 0.f, 0.f, 0.f}, 0, 0, 0);

            const float4 bias = *(const float4*)(b0 + wv * 32 + cm * 16 + quad * 4);
#pragma unroll
            for (int rt = 0; rt < 8; rt++) {
                const int r = rt * 16 + lrow;
                uint2 pk;
                pk.x = pk2bf_(lrelu_(c1[rt][0] + bias.x), lrelu_(c1[rt][1] + bias.y));
                pk.y = pk2bf_(lrelu_(c1[rt][2] + bias.z), lrelu_(c1[rt][3] + bias.w));
                *(uint2*)&sH[r * HPITCH + wv * 32 + cm * 16 + quad * 4] = pk;
            }
        }
    }
    __syncthreads();   // B2

    // ---- GEMM2 via MFMA: 128 reads x 32 cols per wave ----
    f32x4 acc[8][2];
#pragma unroll
    for (int mt = 0; mt < 8; mt++)
#pragma unroll
        for (int nt = 0; nt < 2; nt++)
            acc[mt][nt] = (f32x4){0.f, 0.f, 0.f, 0.f};

#pragma unroll
    for (int kk = 0; kk < 8; kk++) {
        const bf16x8 bn0 = *(const bf16x8*)(w1t + (size_t)(wv * 32 + lrow) * HH + kk * 32 + quad * 8);
        const bf16x8 bn1 = *(const bf16x8*)(w1t + (size_t)(wv * 32 + 16 + lrow) * HH + kk * 32 + quad * 8);
#pragma unroll
        for (int mt = 0; mt < 8; mt++) {
            const bf16x8 am = *(const bf16x8*)&sH[(mt * 16 + lrow) * HPITCH + kk * 32 + quad * 8];
            acc[mt][0] = __builtin_amdgcn_mfma_f32_16x16x32_bf16(am, bn0, acc[mt][0], 0, 0, 0);
            acc[mt][1] = __builtin_amdgcn_mfma_f32_16x16x32_bf16(am, bn1, acc[mt][1], 0, 0, 0);
        }
    }

    // ---- sigmoid in regs ----
#pragma unroll
    for (int nt = 0; nt < 2; nt++) {
        const float bb = b1[wv * 32 + nt * 16 + lrow];
#pragma unroll
        for (int mt = 0; mt < 8; mt++)
#pragma unroll
            for (int r = 0; r < 4; r++)
                acc[mt][nt][r] = sigmoidf_(acc[mt][nt][r] + bb);
    }

    // ---- ballot-driven run-compressed segment reduction, 2 row-groups ----
#pragma unroll
    for (int g = 0; g < 2; g++) {
        const int myseg = seg_ids[sbase + g * 64 + lane];
        const int prev  = __shfl_up(myseg, 1);
        const bool flag = (lane == 0) || (myseg != prev);
        unsigned long long m = __ballot(flag);

        while (m) {
            const int start = (int)__builtin_ctzll(m);
            const unsigned long long m2 = m & (m - 1);
            const int end = m2 ? (int)__builtin_ctzll(m2) : 64;
            m = m2;
            const int seg = __shfl(myseg, start);
            float* srow = sums + (size_t)seg * HH + wv * 32;

            float msk[4][4];
#pragma unroll
            for (int lm = 0; lm < 4; lm++)
#pragma unroll
                for (int r = 0; r < 4; r++) {
                    const int lrw = lm * 16 + quad * 4 + r;   // row within group
                    msk[lm][r] = (lrw >= start && lrw < end) ? 1.0f : 0.0f;
                }
#pragma unroll
            for (int nt = 0; nt < 2; nt++) {
                float s = 0.f;
#pragma unroll
                for (int lm = 0; lm < 4; lm++)
#pragma unroll
                    for (int r = 0; r < 4; r++)
                        s = fmaf(acc[g * 4 + lm][nt][r], msk[lm][r], s);
                s += __shfl_down(s, 32);
                s += __shfl_down(s, 16);
                if (quad == 0)
                    atomicAdd(&srow[nt * 16 + lrow], s);
            }
            if (t == 0) atomicAdd(&cnts[seg], end - start);
        }
    }
}

// ---------------------------------------------------------------------------
// Kernel B: fused MFMA chain (round-6/8 best config).
// ---------------------------------------------------------------------------
__global__ __launch_bounds__(1024, 1) void rho_mfma_kernel(
    const float* __restrict__ info, const int* __restrict__ vtypes,
    const float* __restrict__ om_W0, const float* __restrict__ om_b0,
    const unsigned short* __restrict__ w0t, const float* __restrict__ rho_b0,
    const unsigned short* __restrict__ w1rt, const float* __restrict__ rho_b1,
    const unsigned short* __restrict__ whT, const float* __restrict__ out_b1,
    const float* __restrict__ out_W2, const float* __restrict__ out_b2,
    const float* __restrict__ conf, const float* __restrict__ max_logit,
    const float* __restrict__ ref_sums, const float* __restrict__ alt_sums,
    const int* __restrict__ ref_cnt, const int* __restrict__ alt_cnt,
    float* __restrict__ out)
{
    __shared__ __align__(16) unsigned short sC[TILE_V * CPITCH];
    __shared__ __align__(16) float sInfo[TILE_V][12];
    __shared__ float sRinvR[TILE_V], sRinvA[TILE_V];
    __shared__ float sPart[16][3][TILE_V];

    unsigned short* sA1  = sC;
    unsigned short* sAgg = sC + TILE_V * APITCH;

    const int t  = threadIdx.x;
    const int v0 = blockIdx.x * TILE_V;

    if (t < TILE_V) {
        sRinvR[t] = __builtin_amdgcn_rcpf(fmaxf((float)ref_cnt[v0 + t], 1.0f));
        sRinvA[t] = __builtin_amdgcn_rcpf(fmaxf((float)alt_cnt[v0 + t], 1.0f));
    }
    for (int idx = t; idx < TILE_V * FI; idx += 1024) {
        int i = idx / FI, k = idx - i * FI;
        sInfo[i][k] = info[(size_t)(v0 + i) * FI + k];
    }
    __syncthreads();

    {
        const int c = t & 255, grp = t >> 8;
        float om0r[FI];
#pragma unroll
        for (int k = 0; k < FI; k++) om0r[k] = om_W0[k * HH + c];
        const float omb = om_b0[c];
#pragma unroll
        for (int ii = 0; ii < 8; ii++) {
            const int i = grp * 8 + ii, v = v0 + i;
            float rm = ref_sums[(size_t)v * HH + c] * sRinvR[i];
            float am = alt_sums[(size_t)v * HH + c] * sRinvA[i];
            float a = omb;
#pragma unroll
            for (int k = 0; k < FI; k++) a = fmaf(sInfo[i][k], om0r[k], a);
            sC[i * CPITCH + c]          = f2bf_(rm);
            sC[i * CPITCH + HH + c]     = f2bf_(am);
            sC[i * CPITCH + 2 * HH + c] = f2bf_(sigmoidf_(a));
        }
    }
    __syncthreads();

    const int wv   = t >> 6;
    const int lane = t & 63;
    const int lrow = lane & 15;
    const int quad = lane >> 4;
    const int ncol = wv * 16 + lrow;

    f32x4 p1[2] = {(f32x4){0.f,0.f,0.f,0.f}, (f32x4){0.f,0.f,0.f,0.f}};
#pragma unroll 4
    for (int kk = 0; kk < 24; kk++) {
        bf16x8 a0 = *(const bf16x8*)&sC[lrow * CPITCH + kk * 32 + quad * 8];
        bf16x8 a1 = *(const bf16x8*)&sC[(16 + lrow) * CPITCH + kk * 32 + quad * 8];
        bf16x8 bn = *(const bf16x8*)(w0t + (size_t)ncol * 768 + kk * 32 + quad * 8);
        p1[0] = __builtin_amdgcn_mfma_f32_16x16x32_bf16(a0, bn, p1[0], 0, 0, 0);
        p1[1] = __builtin_amdgcn_mfma_f32_16x16x32_bf16(a1, bn, p1[1], 0, 0, 0);
    }
    __syncthreads();
    {
        const float bb = rho_b0[ncol];
#pragma unroll
        for (int mt = 0; mt < 2; mt++)
#pragma unroll
            for (int r = 0; r < 4; r++) {
                const int row = mt * 16 + quad * 4 + r;
                sA1[row * APITCH + ncol] = f2bf_(lrelu_(p1[mt][r] + bb));
            }
    }
    __syncthreads();

    f32x4 p2[2] = {(f32x4){0.f,0.f,0.f,0.f}, (f32x4){0.f,0.f,0.f,0.f}};
#pragma unroll
    for (int kk = 0; kk < 8; kk++) {
        bf16x8 a0 = *(const bf16x8*)&sA1[lrow * APITCH + kk * 32 + quad * 8];
        bf16x8 a1 = *(const bf16x8*)&sA1[(16 + lrow) * APITCH + kk * 32 + quad * 8];
        bf16x8 bn = *(const bf16x8*)(w1rt + (size_t)ncol * HH + kk * 32 + quad * 8);
        p2[0] = __builtin_amdgcn_mfma_f32_16x16x32_bf16(a0, bn, p2[0], 0, 0, 0);
        p2[1] = __builtin_amdgcn_mfma_f32_16x16x32_bf16(a1, bn, p2[1], 0, 0, 0);
    }
    {
        const float bb = rho_b1[ncol];
#pragma unroll
        for (int mt = 0; mt < 2; mt++)
#pragma unroll
            for (int r = 0; r < 4; r++) {
                const int row = mt * 16 + quad * 4 + r;
                sAgg[row * APITCH + ncol] = f2bf_(p2[mt][r] + bb);
            }
    }
    __syncthreads();

    bf16x8 aF[8][2];
#pragma unroll
    for (int kk = 0; kk < 8; kk++)
#pragma unroll
        for (int mt = 0; mt < 2; mt++)
            aF[kk][mt] = *(const bf16x8*)&sAgg[(mt * 16 + lrow) * APITCH + kk * 32 + quad * 8];

    for (int h = 0; h < 3; h++) {
        f32x4 p3[2] = {(f32x4){0.f,0.f,0.f,0.f}, (f32x4){0.f,0.f,0.f,0.f}};
#pragma unroll
        for (int kk = 0; kk < 8; kk++) {
            bf16x8 bn = *(const bf16x8*)(whT + ((size_t)h * HH + ncol) * HH + kk * 32 + quad * 8);
            p3[0] = __builtin_amdgcn_mfma_f32_16x16x32_bf16(aF[kk][0], bn, p3[0], 0, 0, 0);
            p3[1] = __builtin_amdgcn_mfma_f32_16x16x32_bf16(aF[kk][1], bn, p3[1], 0, 0, 0);
        }
        const float bb = out_b1[h * HH + ncol];
        const float w2 = out_W2[h * HH + ncol];
#pragma unroll
        for (int mt = 0; mt < 2; mt++)
#pragma unroll
            for (int r = 0; r < 4; r++) {
                float v = lrelu_(p3[mt][r] + bb) * w2;
                v += __shfl_down(v, 8);
                v += __shfl_down(v, 4);
                v += __shfl_down(v, 2);
                v += __shfl_down(v, 1);
                if (lrow == 0) sPart[wv][h][mt * 16 + quad * 4 + r] = v;
            }
    }
    __syncthreads();

    if (t < TILE_V) {
        const int v = v0 + t;
        const int ty = vtypes[v];
        float logit = 0.f;
#pragma unroll
        for (int w = 0; w < 16; w++) logit += sPart[w][ty][t];
        logit += out_b2[ty];
        const int tr = min(alt_cnt[v], MAX_ALT);
        logit *= conf[tr];
        const float ml = max_logit[0];
        out[v] = ml * tanhf(logit / ml);
    }
}

// ---------------------------------------------------------------------------
extern "C" void kernel_launch(void* const* d_in, const int* in_sizes, int n_in,
                              void* d_out, int out_size, void* d_ws, size_t ws_size,
                              hipStream_t stream) {
    const float* reads    = (const float*)d_in[0];
    const float* info     = (const float*)d_in[1];
    const int*   ref_ids  = (const int*)d_in[2];
    const int*   alt_ids  = (const int*)d_in[3];
    const int*   vtypes   = (const int*)d_in[4];
    const float* phi_W0   = (const float*)d_in[5];
    const float* phi_b0   = (const float*)d_in[6];
    const float* phi_W1   = (const float*)d_in[7];
    const float* phi_b1   = (const float*)d_in[8];
    const float* om_W0    = (const float*)d_in[9];
    const float* om_b0    = (const float*)d_in[10];
    const float* rho_W0   = (const float*)d_in[11];
    const float* rho_b0   = (const float*)d_in[12];
    const float* rho_W1   = (const float*)d_in[13];
    const float* rho_b1   = (const float*)d_in[14];
    const float* out_W1   = (const float*)d_in[15];
    const float* out_b1   = (const float*)d_in[16];
    const float* out_W2   = (const float*)d_in[17];
    const float* out_b2   = (const float*)d_in[18];
    const float* conf     = (const float*)d_in[19];
    const float* max_lg   = (const float*)d_in[20];
    float* out = (float*)d_out;

    float* ref_sums = (float*)d_ws;
    float* alt_sums = ref_sums + (size_t)V * HH;
    int*   ref_cnt  = (int*)(alt_sums + (size_t)V * HH);
    int*   alt_cnt  = ref_cnt + V;
    unsigned short* w1t_phi = (unsigned short*)(alt_cnt + V);
    unsigned short* w0t     = w1t_phi + (size_t)HH * HH;
    unsigned short* w1rt    = w0t + (size_t)HH * 768;
    unsigned short* whT     = w1rt + (size_t)HH * HH;
    unsigned short* w0pT    = whT + (size_t)3 * HH * HH;

    prep_kernel<<<1568, 256, 0, stream>>>(phi_W1, rho_W0, rho_W1, out_W1, phi_W0,
                                          w1t_phi, w0t, w1rt, whT, w0pT,
                                          (float*)d_ws);

    phi_seg_kernel<<<NREADS / TILE_R, 512, 0, stream>>>(
        reads, ref_ids, alt_ids, w0pT, phi_b0, w1t_phi, phi_b1,
        ref_sums, alt_sums, ref_cnt, alt_cnt);

    rho_mfma_kernel<<<V / TILE_V, 1024, 0, stream>>>(
        info, vtypes, om_W0, om_b0, w0t, rho_b0, w1rt, rho_b1,
        whT, out_b1, out_W2, out_b2, conf, max_lg,
        ref_sums, alt_sums, ref_cnt, alt_cnt, out);
}